// Round 4
// baseline (290.088 us; speedup 1.0000x reference)
//
#include <hip/hip_runtime.h>

// Problem constants (from reference)
#define N_PTS 8388608
#define FX 758.03967f
#define CXC 621.46572f
#define FY 761.62359f
#define CYC 756.86402f
#define U_MAX 1231.0f   // WIDTH - 1
#define W_MAX 1615.0f   // HEIGHT - 1
#define MIN_D 1.0f
#define MAX_D_R 10.0f
#define MAX_D_M 5.0f

#define PTS_PER_THREAD 8
#define THREADS 256
#define N_THREADS_TOT (N_PTS / PTS_PER_THREAD)   // 1048576
#define N_BLOCKS (N_THREADS_TOT / THREADS)       // 4096
#define N_WAVES (N_THREADS_TOT / 64)             // 16384

// native clang vector: __builtin_nontemporal_store requires it (HIP float4 is a class)
typedef float vfloat4 __attribute__((ext_vector_type(4)));

// Workspace layout (32-bit units):
//   [0..8]   R row-major, [9..11] t
//   [16 + w] (w in [0,16384)) : per-wave partial counts (always written, no init needed)

__global__ void pose_setup_kernel(const float* __restrict__ x, const float* __restrict__ y,
                                  const float* __restrict__ z, const float* __restrict__ roll,
                                  const float* __restrict__ pitch, const float* __restrict__ yaw,
                                  float* __restrict__ ws) {
    float cr = cosf(*roll), sr = sinf(*roll);
    float cp = cosf(*pitch), sp = sinf(*pitch);
    float cy = cosf(*yaw),  sy = sinf(*yaw);
    // R = Rx(roll) @ Ry(pitch) @ Rz(yaw), row-major. At the zero pose this is
    // exactly identity (with signed zeros), so v = points bit-exact.
    ws[0] = cp * cy;                ws[1] = -(cp * sy);             ws[2] = sp;
    ws[3] = cr * sy + sr * sp * cy; ws[4] = cr * cy - sr * sp * sy; ws[5] = -(sr * cp);
    ws[6] = sr * sy - cr * sp * cy; ws[7] = sr * cy + cr * sp * sy; ws[8] = cr * cp;
    ws[9] = *x; ws[10] = *y; ws[11] = *z;
}

// No LDS, no __syncthreads, no atomics: R2's block tail (6-dep shfl chain +
// barrier-with-vmcnt(0)-drain + 128-deep per-slot atomic chains) held waves
// resident ~23K cycles for ~200 cycles of VALU work. Ballot+popc gives a
// wave-uniform count; one plain 4B store per wave replaces the atomic.
__global__ __launch_bounds__(256) void frustum_kernel(const vfloat4* __restrict__ pts,
                                                      const float* __restrict__ ws,
                                                      vfloat4* __restrict__ out,
                                                      unsigned int* __restrict__ parts) {
    const float R0 = ws[0], R1 = ws[1], R2 = ws[2];
    const float R3 = ws[3], R4 = ws[4], R5 = ws[5];
    const float R6 = ws[6], R7 = ws[7], R8 = ws[8];
    const float t0 = ws[9], t1 = ws[10], t2 = ws[11];

    const int tid = blockIdx.x * THREADS + threadIdx.x;  // one thread = 8 points = 6 float4
    const long base = (long)tid * 6;

    union Pack { vfloat4 v[6]; float f[24]; };
    Pack in, o;
#pragma unroll
    for (int i = 0; i < 6; ++i) in.v[i] = pts[base + i];

    int cnt = 0;
#pragma unroll
    for (int p = 0; p < PTS_PER_THREAD; ++p) {
        float d0 = in.f[p * 3 + 0] - t0;
        float d1 = in.f[p * 3 + 1] - t1;
        float d2 = in.f[p * 3 + 2] - t2;
        // ascending-k fma accumulation to match the numpy reference's matmul
        float v0 = fmaf(d2, R6, fmaf(d1, R3, d0 * R0));
        float v1 = fmaf(d2, R7, fmaf(d1, R4, d0 * R1));
        float v2 = fmaf(d2, R8, fmaf(d1, R5, d0 * R2));
        float p0 = fmaf(v2, CXC, v0 * FX);
        float p1 = fmaf(v2, CYC, v1 * FY);
        float u = p0 / v2;   // IEEE div; inf/nan on v2==0 compares false, same as numpy
        float w = p1 / v2;
        bool fov = (v2 > 0.0f) && (u > 1.0f) && (u < U_MAX) && (w > 1.0f) && (w < W_MAX);
        bool rew = fov && (v2 > MIN_D) && (v2 < MAX_D_R);
        cnt += (int)__popcll(__ballot(rew));   // wave-uniform, pure VALU/SALU
        bool m = fov && (v2 > MIN_D) && (v2 < MAX_D_M);
        o.f[p * 3 + 0] = m ? v0 : 0.0f;
        o.f[p * 3 + 1] = m ? v1 : 0.0f;
        o.f[p * 3 + 2] = m ? v2 : 0.0f;
    }

    // out is never re-read: non-temporal keeps L3 for the points stream
#pragma unroll
    for (int i = 0; i < 6; ++i)
        __builtin_nontemporal_store(o.v[i], &out[base + i]);

    if ((threadIdx.x & 63) == 0)
        parts[tid >> 6] = (unsigned int)cnt;   // one plain 4B store per wave
}

__global__ __launch_bounds__(256) void finalize_kernel(const unsigned int* __restrict__ parts,
                                                       float* __restrict__ out) {
    unsigned int s = 0;
    for (int i = threadIdx.x; i < N_WAVES; i += THREADS) s += parts[i];
    for (int off = 32; off > 0; off >>= 1) s += __shfl_down(s, off, 64);
    __shared__ unsigned int red[4];
    if ((threadIdx.x & 63) == 0) red[threadIdx.x >> 6] = s;
    __syncthreads();
    if (threadIdx.x == 0) {
        unsigned int c = red[0] + red[1] + red[2] + red[3];
        out[(long)3 * N_PTS] = 1.0f / ((float)c + 1e-6f);
    }
}

extern "C" void kernel_launch(void* const* d_in, const int* in_sizes, int n_in,
                              void* d_out, int out_size, void* d_ws, size_t ws_size,
                              hipStream_t stream) {
    const float* points = (const float*)d_in[0];
    const float* x      = (const float*)d_in[1];
    const float* y      = (const float*)d_in[2];
    const float* z      = (const float*)d_in[3];
    const float* roll   = (const float*)d_in[4];
    const float* pitch  = (const float*)d_in[5];
    const float* yaw    = (const float*)d_in[6];
    float* ws = (float*)d_ws;
    unsigned int* parts = (unsigned int*)ws + 16;
    float* out = (float*)d_out;

    pose_setup_kernel<<<1, 1, 0, stream>>>(x, y, z, roll, pitch, yaw, ws);
    frustum_kernel<<<N_BLOCKS, THREADS, 0, stream>>>((const vfloat4*)points, ws,
                                                     (vfloat4*)out, parts);
    finalize_kernel<<<1, THREADS, 0, stream>>>(parts, out);
}

// Round 5
// 207.074 us; speedup vs baseline: 1.4009x; 1.4009x over previous
//
#include <hip/hip_runtime.h>

// Problem constants (from reference)
#define N_PTS 8388608
#define FX 758.03967f
#define CXC 621.46572f
#define FY 761.62359f
#define CYC 756.86402f
#define U_MAX 1231.0f   // WIDTH - 1
#define W_MAX 1615.0f   // HEIGHT - 1
#define MIN_D 1.0f
#define MAX_D_R 10.0f
#define MAX_D_M 5.0f

#define PTS_PER_THREAD 8
#define THREADS 256
#define N_THREADS_TOT (N_PTS / PTS_PER_THREAD)   // 1048576
#define N_BLOCKS (N_THREADS_TOT / THREADS)       // 4096
#define N_WAVES (N_THREADS_TOT / 64)             // 16384

typedef float vfloat4 __attribute__((ext_vector_type(4)));

// Workspace layout (32-bit units):
//   [0..8]   R row-major, [9..11] t
//   [16 + w] (w in [0,16384)) : per-wave partial counts (always written, no init needed)

__global__ void pose_setup_kernel(const float* __restrict__ x, const float* __restrict__ y,
                                  const float* __restrict__ z, const float* __restrict__ roll,
                                  const float* __restrict__ pitch, const float* __restrict__ yaw,
                                  float* __restrict__ ws) {
    float cr = cosf(*roll), sr = sinf(*roll);
    float cp = cosf(*pitch), sp = sinf(*pitch);
    float cy = cosf(*yaw),  sy = sinf(*yaw);
    // R = Rx(roll) @ Ry(pitch) @ Rz(yaw), row-major. At the zero pose this is
    // exactly identity (with signed zeros), so v = points bit-exact.
    ws[0] = cp * cy;                ws[1] = -(cp * sy);             ws[2] = sp;
    ws[3] = cr * sy + sr * sp * cy; ws[4] = cr * cy - sr * sp * sy; ws[5] = -(sr * cp);
    ws[6] = sr * sy - cr * sp * cy; ws[7] = sr * cy + cr * sp * sy; ws[8] = cr * cp;
    ws[9] = *x; ws[10] = *y; ws[11] = *z;
}

// No LDS, no __syncthreads, no atomics (R2's block tail stalled waves).
// PLAIN stores: R4 showed nt stores bypass L2's partial-line merging on the
// 96B-lane-stride pattern -> WRITE_SIZE 99->237 MB (RMW amplification).
// L2 merges the wave's 6 partial-line store instructions into full lines.
__global__ __launch_bounds__(256) void frustum_kernel(const vfloat4* __restrict__ pts,
                                                      const float* __restrict__ ws,
                                                      vfloat4* __restrict__ out,
                                                      unsigned int* __restrict__ parts) {
    const float R0 = ws[0], R1 = ws[1], R2 = ws[2];
    const float R3 = ws[3], R4 = ws[4], R5 = ws[5];
    const float R6 = ws[6], R7 = ws[7], R8 = ws[8];
    const float t0 = ws[9], t1 = ws[10], t2 = ws[11];

    const int tid = blockIdx.x * THREADS + threadIdx.x;  // one thread = 8 points = 6 float4
    const long base = (long)tid * 6;

    union Pack { vfloat4 v[6]; float f[24]; };
    Pack in, o;
#pragma unroll
    for (int i = 0; i < 6; ++i) in.v[i] = pts[base + i];

    int cnt = 0;
#pragma unroll
    for (int p = 0; p < PTS_PER_THREAD; ++p) {
        float d0 = in.f[p * 3 + 0] - t0;
        float d1 = in.f[p * 3 + 1] - t1;
        float d2 = in.f[p * 3 + 2] - t2;
        // ascending-k fma accumulation to match the numpy reference's matmul
        float v0 = fmaf(d2, R6, fmaf(d1, R3, d0 * R0));
        float v1 = fmaf(d2, R7, fmaf(d1, R4, d0 * R1));
        float v2 = fmaf(d2, R8, fmaf(d1, R5, d0 * R2));
        float p0 = fmaf(v2, CXC, v0 * FX);
        float p1 = fmaf(v2, CYC, v1 * FY);
        float u = p0 / v2;   // IEEE div; inf/nan on v2==0 compares false, same as numpy
        float w = p1 / v2;
        bool fov = (v2 > 0.0f) && (u > 1.0f) && (u < U_MAX) && (w > 1.0f) && (w < W_MAX);
        bool rew = fov && (v2 > MIN_D) && (v2 < MAX_D_R);
        cnt += (int)__popcll(__ballot(rew));   // wave-uniform, pure VALU/SALU
        bool m = fov && (v2 > MIN_D) && (v2 < MAX_D_M);
        o.f[p * 3 + 0] = m ? v0 : 0.0f;
        o.f[p * 3 + 1] = m ? v1 : 0.0f;
        o.f[p * 3 + 2] = m ? v2 : 0.0f;
    }

#pragma unroll
    for (int i = 0; i < 6; ++i)
        out[base + i] = o.v[i];

    if ((threadIdx.x & 63) == 0)
        parts[tid >> 6] = (unsigned int)cnt;   // one plain 4B store per wave
}

__global__ __launch_bounds__(256) void finalize_kernel(const unsigned int* __restrict__ parts,
                                                       float* __restrict__ out) {
    unsigned int s = 0;
    for (int i = threadIdx.x; i < N_WAVES; i += THREADS) s += parts[i];
    for (int off = 32; off > 0; off >>= 1) s += __shfl_down(s, off, 64);
    __shared__ unsigned int red[4];
    if ((threadIdx.x & 63) == 0) red[threadIdx.x >> 6] = s;
    __syncthreads();
    if (threadIdx.x == 0) {
        unsigned int c = red[0] + red[1] + red[2] + red[3];
        out[(long)3 * N_PTS] = 1.0f / ((float)c + 1e-6f);
    }
}

extern "C" void kernel_launch(void* const* d_in, const int* in_sizes, int n_in,
                              void* d_out, int out_size, void* d_ws, size_t ws_size,
                              hipStream_t stream) {
    const float* points = (const float*)d_in[0];
    const float* x      = (const float*)d_in[1];
    const float* y      = (const float*)d_in[2];
    const float* z      = (const float*)d_in[3];
    const float* roll   = (const float*)d_in[4];
    const float* pitch  = (const float*)d_in[5];
    const float* yaw    = (const float*)d_in[6];
    float* ws = (float*)d_ws;
    unsigned int* parts = (unsigned int*)ws + 16;
    float* out = (float*)d_out;

    pose_setup_kernel<<<1, 1, 0, stream>>>(x, y, z, roll, pitch, yaw, ws);
    frustum_kernel<<<N_BLOCKS, THREADS, 0, stream>>>((const vfloat4*)points, ws,
                                                     (vfloat4*)out, parts);
    finalize_kernel<<<1, THREADS, 0, stream>>>(parts, out);
}

// Round 6
// 201.839 us; speedup vs baseline: 1.4372x; 1.0259x over previous
//
#include <hip/hip_runtime.h>

// Problem constants (from reference)
#define N_PTS 8388608
#define FX 758.03967f
#define CXC 621.46572f
#define FY 761.62359f
#define CYC 756.86402f
#define U_MAX 1231.0f   // WIDTH - 1
#define W_MAX 1615.0f   // HEIGHT - 1
#define MIN_D 1.0f
#define MAX_D_R 10.0f
#define MAX_D_M 5.0f

#define PTS_PER_THREAD 8
#define THREADS 256
#define BLOCK_PTS (THREADS * PTS_PER_THREAD)   // 2048 points per block
#define BLOCK_F4  (BLOCK_PTS * 3 / 4)          // 1536 float4 per block
#define N_BLOCKS  (N_PTS / BLOCK_PTS)          // 4096
#define N_WAVES   (N_BLOCKS * 4)               // 16384

typedef float vfloat4 __attribute__((ext_vector_type(4)));

// Workspace layout (32-bit units):
//   [0..8]   R row-major, [9..11] t
//   [16 + w] (w in [0,16384)) : per-wave partial counts (always written, no init needed)

__global__ void pose_setup_kernel(const float* __restrict__ x, const float* __restrict__ y,
                                  const float* __restrict__ z, const float* __restrict__ roll,
                                  const float* __restrict__ pitch, const float* __restrict__ yaw,
                                  float* __restrict__ ws) {
    float cr = cosf(*roll), sr = sinf(*roll);
    float cp = cosf(*pitch), sp = sinf(*pitch);
    float cy = cosf(*yaw),  sy = sinf(*yaw);
    // R = Rx(roll) @ Ry(pitch) @ Rz(yaw), row-major. At the zero pose this is
    // exactly identity (with signed zeros), so v = points bit-exact.
    ws[0] = cp * cy;                ws[1] = -(cp * sy);             ws[2] = sp;
    ws[3] = cr * sy + sr * sp * cy; ws[4] = cr * cy - sr * sp * sy; ws[5] = -(sr * cp);
    ws[6] = sr * sy - cr * sp * cy; ws[7] = sr * cy + cr * sp * sy; ws[8] = cr * cp;
    ws[9] = *x; ws[10] = *y; ws[11] = *z;
}

// R2==R5 (61 vs 64.5 us with/without the block tail) falsified the tail
// theory: the limiter is the 96B-lane-stride float4 pattern (64 partial
// lines per vmem instr -> address-unit line sequencing, ~request-rate
// bound at 3.1 TB/s while VALU/HBM idle). Fix: LDS staging so every
// global access is wave-dense; compute phase reads LDS at dword-stride 3
// (gcd(3,32)=1 -> 2 lanes/bank = free per m136).
__global__ __launch_bounds__(256) void frustum_kernel(const vfloat4* __restrict__ pts4,
                                                      const float* __restrict__ ws,
                                                      vfloat4* __restrict__ out4,
                                                      unsigned int* __restrict__ parts) {
    __shared__ float lds_f[BLOCK_PTS * 3];          // 6144 floats = 24 KB
    vfloat4* lds4 = (vfloat4*)lds_f;

    const float R0 = ws[0], R1 = ws[1], R2 = ws[2];
    const float R3 = ws[3], R4 = ws[4], R5 = ws[5];
    const float R6 = ws[6], R7 = ws[7], R8 = ws[8];
    const float t0 = ws[9], t1 = ws[10], t2 = ws[11];

    const int tid = threadIdx.x;
    const long gbase4 = (long)blockIdx.x * BLOCK_F4;

    // Phase 1: dense global -> LDS (each instr: wave covers contiguous 1 KB)
#pragma unroll
    for (int k = 0; k < 6; ++k)
        lds4[k * THREADS + tid] = pts4[gbase4 + k * THREADS + tid];
    __syncthreads();

    // Phase 2: thread t owns block-local points {t + 256j}; LDS addrs are
    // thread-private so in-place rewrite needs no intra-phase barrier.
    int cnt = 0;
#pragma unroll
    for (int j = 0; j < PTS_PER_THREAD; ++j) {
        const int f = 3 * tid + j * (3 * THREADS);
        float d0 = lds_f[f + 0] - t0;
        float d1 = lds_f[f + 1] - t1;
        float d2 = lds_f[f + 2] - t2;
        // ascending-k fma accumulation to match the numpy reference's matmul
        float v0 = fmaf(d2, R6, fmaf(d1, R3, d0 * R0));
        float v1 = fmaf(d2, R7, fmaf(d1, R4, d0 * R1));
        float v2 = fmaf(d2, R8, fmaf(d1, R5, d0 * R2));
        float p0 = fmaf(v2, CXC, v0 * FX);
        float p1 = fmaf(v2, CYC, v1 * FY);
        float u = p0 / v2;   // IEEE div; inf/nan on v2==0 compares false, same as numpy
        float w = p1 / v2;
        bool fov = (v2 > 0.0f) && (u > 1.0f) && (u < U_MAX) && (w > 1.0f) && (w < W_MAX);
        bool rew = fov && (v2 > MIN_D) && (v2 < MAX_D_R);
        cnt += (int)__popcll(__ballot(rew));   // wave-uniform, no reduction tail
        bool m = fov && (v2 > MIN_D) && (v2 < MAX_D_M);
        lds_f[f + 0] = m ? v0 : 0.0f;
        lds_f[f + 1] = m ? v1 : 0.0f;
        lds_f[f + 2] = m ? v2 : 0.0f;
    }
    __syncthreads();

    // Phase 3: dense LDS -> global
#pragma unroll
    for (int k = 0; k < 6; ++k)
        out4[gbase4 + k * THREADS + tid] = lds4[k * THREADS + tid];

    if ((tid & 63) == 0)
        parts[blockIdx.x * 4 + (tid >> 6)] = (unsigned int)cnt;
}

__global__ __launch_bounds__(256) void finalize_kernel(const unsigned int* __restrict__ parts,
                                                       float* __restrict__ out) {
    unsigned int s = 0;
    for (int i = threadIdx.x; i < N_WAVES; i += THREADS) s += parts[i];
    for (int off = 32; off > 0; off >>= 1) s += __shfl_down(s, off, 64);
    __shared__ unsigned int red[4];
    if ((threadIdx.x & 63) == 0) red[threadIdx.x >> 6] = s;
    __syncthreads();
    if (threadIdx.x == 0) {
        unsigned int c = red[0] + red[1] + red[2] + red[3];
        out[(long)3 * N_PTS] = 1.0f / ((float)c + 1e-6f);
    }
}

extern "C" void kernel_launch(void* const* d_in, const int* in_sizes, int n_in,
                              void* d_out, int out_size, void* d_ws, size_t ws_size,
                              hipStream_t stream) {
    const float* points = (const float*)d_in[0];
    const float* x      = (const float*)d_in[1];
    const float* y      = (const float*)d_in[2];
    const float* z      = (const float*)d_in[3];
    const float* roll   = (const float*)d_in[4];
    const float* pitch  = (const float*)d_in[5];
    const float* yaw    = (const float*)d_in[6];
    float* ws = (float*)d_ws;
    unsigned int* parts = (unsigned int*)ws + 16;
    float* out = (float*)d_out;

    pose_setup_kernel<<<1, 1, 0, stream>>>(x, y, z, roll, pitch, yaw, ws);
    frustum_kernel<<<N_BLOCKS, THREADS, 0, stream>>>((const vfloat4*)points, ws,
                                                     (vfloat4*)out, parts);
    finalize_kernel<<<1, THREADS, 0, stream>>>(parts, out);
}

// Round 7
// 197.916 us; speedup vs baseline: 1.4657x; 1.0198x over previous
//
#include <hip/hip_runtime.h>

// Problem constants (from reference)
#define N_PTS 8388608
#define N_F4 (N_PTS * 3 / 4)                      // 6291456 float4s in/out
#define FX 758.03967f
#define CXC 621.46572f
#define FY 761.62359f
#define CYC 756.86402f
#define U_MAX 1231.0f   // WIDTH - 1
#define W_MAX 1615.0f   // HEIGHT - 1
#define MIN_D 1.0f
#define MAX_D_R 10.0f
#define MAX_D_M 5.0f

#define THREADS 256
#define GRID_BLOCKS 2048                          // 8 blocks/CU -> full 32 waves/CU
#define TOTAL_THREADS (GRID_BLOCKS * THREADS)     // 524288
#define ITERS (N_F4 / TOTAL_THREADS)              // 12, exact
#define N_WAVES_G (GRID_BLOCKS * (THREADS / 64))  // 8192

typedef float vfloat4 __attribute__((ext_vector_type(4)));

// Workspace layout (32-bit units):
//   [0..8] R row-major, [9..11] t
//   [16 + w] (w in [0,8192)) : per-wave partial counts (always written)

__global__ void pose_setup_kernel(const float* __restrict__ x, const float* __restrict__ y,
                                  const float* __restrict__ z, const float* __restrict__ roll,
                                  const float* __restrict__ pitch, const float* __restrict__ yaw,
                                  float* __restrict__ ws) {
    float cr = cosf(*roll), sr = sinf(*roll);
    float cp = cosf(*pitch), sp = sinf(*pitch);
    float cy = cosf(*yaw),  sy = sinf(*yaw);
    // R = Rx(roll) @ Ry(pitch) @ Rz(yaw), row-major. At the zero pose this is
    // exactly identity (with signed zeros), so v = points bit-exact.
    ws[0] = cp * cy;                ws[1] = -(cp * sy);             ws[2] = sp;
    ws[3] = cr * sy + sr * sp * cy; ws[4] = cr * cy - sr * sp * sy; ws[5] = -(sr * cp);
    ws[6] = sr * sy - cr * sp * cy; ws[7] = sr * cy + cr * sp * sy; ws[8] = cr * cp;
    ws[9] = *x; ws[10] = *y; ws[11] = *z;
}

// R2(strided+tail) ~ R5(strided, no tail) ~ R6(LDS dense, barriers) ~ 60us:
// each structure kept one limiter (TA partial-line sequencing OR barrier
// convoying). This version has NEITHER: dense float4 load/store per lane,
// float3 boundary floats fetched from lane+-1 via shuffle (edge lanes
// re-load 2 floats from global, L1-hit), 2 redundant point-transforms per
// lane, phase-select of the 4 output floats. No LDS, no barriers, no
// atomics; persistent grid (32 waves/CU) for latency hiding.
__global__ __launch_bounds__(256) void stream_kernel(const float* __restrict__ ptsf,
                                                     const float* __restrict__ ws,
                                                     vfloat4* __restrict__ out4,
                                                     unsigned int* __restrict__ parts) {
    const float R0 = ws[0], R1 = ws[1], R2 = ws[2];
    const float R3 = ws[3], R4 = ws[4], R5 = ws[5];
    const float R6 = ws[6], R7 = ws[7], R8 = ws[8];
    const float t0 = ws[9], t1 = ws[10], t2 = ws[11];
    const vfloat4* pts4 = (const vfloat4*)ptsf;

    const int lane = threadIdx.x & 63;
    int cnt = 0;

    auto xform = [&](float px, float py, float pz, float& v0, float& v1, float& v2,
                     bool& rew, bool& vis) {
        float d0 = px - t0, d1 = py - t1, d2 = pz - t2;
        // ascending-k fma accumulation to match the numpy reference's matmul
        v0 = fmaf(d2, R6, fmaf(d1, R3, d0 * R0));
        v1 = fmaf(d2, R7, fmaf(d1, R4, d0 * R1));
        v2 = fmaf(d2, R8, fmaf(d1, R5, d0 * R2));
        float p0 = fmaf(v2, CXC, v0 * FX);
        float p1 = fmaf(v2, CYC, v1 * FY);
        float u = p0 / v2;   // IEEE div; inf/nan on v2==0 compares false, same as numpy
        float w = p1 / v2;
        bool fov = (v2 > 0.0f) && (u > 1.0f) && (u < U_MAX) && (w > 1.0f) && (w < W_MAX);
        rew = fov && (v2 > MIN_D) && (v2 < MAX_D_R);
        vis = fov && (v2 > MIN_D) && (v2 < MAX_D_M);
    };

    for (int it = 0; it < ITERS; ++it) {
        const int gid = it * TOTAL_THREADS + blockIdx.x * THREADS + threadIdx.x;
        vfloat4 m = pts4[gid];
        const int phase = gid % 3;        // == (4*gid) % 3, since 4 = 1 mod 3
        const int g0 = gid * 4;           // global float index of m.x

        // boundary floats from neighbor lanes (dense float4s are contiguous across lanes)
        float p1f = __shfl_up(m.w, 1, 64);     // float g0-1
        float p2f = __shfl_up(m.z, 1, 64);     // float g0-2
        float n1f = __shfl_down(m.x, 1, 64);   // float g0+4
        float n2f = __shfl_down(m.y, 1, 64);   // float g0+5
        if (lane == 0 && phase != 0) { p2f = ptsf[g0 - 2]; p1f = ptsf[g0 - 1]; }
        if (lane == 63 && phase != 2) { n1f = ptsf[g0 + 4]; n2f = ptsf[g0 + 5]; }

        // the two points overlapping this lane's 4 floats
        float ax = phase == 0 ? m.x : (phase == 1 ? p1f : p2f);
        float ay = phase == 0 ? m.y : (phase == 1 ? m.x : p1f);
        float az = phase == 0 ? m.z : (phase == 1 ? m.y : m.x);
        float bx = phase == 0 ? m.w : (phase == 1 ? m.z : m.y);
        float by = phase == 0 ? n1f : (phase == 1 ? m.w : m.z);
        float bz = phase == 0 ? n2f : (phase == 1 ? n1f : m.w);

        float A0, A1, A2, B0, B1, B2;
        bool rA, vA, rB, vB;
        xform(ax, ay, az, A0, A1, A2, rA, vA);
        xform(bx, by, bz, B0, B1, B2, rB, vB);
        A0 = vA ? A0 : 0.0f; A1 = vA ? A1 : 0.0f; A2 = vA ? A2 : 0.0f;
        B0 = vB ? B0 : 0.0f; B1 = vB ? B1 : 0.0f; B2 = vB ? B2 : 0.0f;

        // point p is counted by the unique lane whose float4 contains float 3p:
        // phase 0 -> both A and B start here; phase 1/2 -> only B does.
        cnt += (int)__popcll(__ballot(rA && phase == 0));
        cnt += (int)__popcll(__ballot(rB));

        vfloat4 o;   // o[c] = value for global float g0+c
        o.x = phase == 0 ? A0 : (phase == 1 ? A1 : A2);
        o.y = phase == 0 ? A1 : (phase == 1 ? A2 : B0);
        o.z = phase == 0 ? A2 : (phase == 1 ? B0 : B1);
        o.w = phase == 0 ? B0 : (phase == 1 ? B1 : B2);
        out4[gid] = o;
    }

    if (lane == 0)
        parts[(blockIdx.x << 2) + (threadIdx.x >> 6)] = (unsigned int)cnt;
}

__global__ __launch_bounds__(256) void finalize_kernel(const unsigned int* __restrict__ parts,
                                                       float* __restrict__ out) {
    unsigned int s = 0;
    for (int i = threadIdx.x; i < N_WAVES_G; i += THREADS) s += parts[i];
    for (int off = 32; off > 0; off >>= 1) s += __shfl_down(s, off, 64);
    __shared__ unsigned int red[4];
    if ((threadIdx.x & 63) == 0) red[threadIdx.x >> 6] = s;
    __syncthreads();
    if (threadIdx.x == 0) {
        unsigned int c = red[0] + red[1] + red[2] + red[3];
        out[(long)3 * N_PTS] = 1.0f / ((float)c + 1e-6f);
    }
}

extern "C" void kernel_launch(void* const* d_in, const int* in_sizes, int n_in,
                              void* d_out, int out_size, void* d_ws, size_t ws_size,
                              hipStream_t stream) {
    const float* points = (const float*)d_in[0];
    const float* x      = (const float*)d_in[1];
    const float* y      = (const float*)d_in[2];
    const float* z      = (const float*)d_in[3];
    const float* roll   = (const float*)d_in[4];
    const float* pitch  = (const float*)d_in[5];
    const float* yaw    = (const float*)d_in[6];
    float* ws = (float*)d_ws;
    unsigned int* parts = (unsigned int*)ws + 16;
    float* out = (float*)d_out;

    pose_setup_kernel<<<1, 1, 0, stream>>>(x, y, z, roll, pitch, yaw, ws);
    stream_kernel<<<GRID_BLOCKS, THREADS, 0, stream>>>(points, ws, (vfloat4*)out, parts);
    finalize_kernel<<<1, THREADS, 0, stream>>>(parts, out);
}